// Round 20
// baseline (184.899 us; speedup 1.0000x reference)
//
#include <hip/hip_runtime.h>

typedef __attribute__((ext_vector_type(8))) short short8;
typedef __attribute__((ext_vector_type(4))) float f32x4;
typedef __attribute__((ext_vector_type(16))) float f32x16;
typedef __attribute__((ext_vector_type(4))) ushort u16x4;

constexpr int NN = 10000;
constexpr int NE = 160000;
constexpr int NT32 = NE / 32;                  // 5000 32-edge tiles
constexpr int TPSTR = 64;                      // tp row stride in ushort (128 B)
constexpr int GBLK = 625;
constexpr float EPSV = 1e-5f;
constexpr float INV3 = 0.57735026918962576f;
constexpr float ALPHA = 0.20412414523193152f;

__device__ __forceinline__ ushort f2bf(float x) {
  unsigned u = __float_as_uint(x);
  u += 0x7fffu + ((u >> 16) & 1u);
  return (ushort)(u >> 16);
}
__device__ __forceinline__ float bf2f(ushort u) {
  return __uint_as_float(((unsigned)u) << 16);
}
__device__ __forceinline__ f32x16 mfma32(short8 a, short8 b, f32x16 c) {
  return __builtin_amdgcn_mfma_f32_32x32x16_bf16(a, b, c, 0, 0, 0);
}
__device__ __forceinline__ void st4u(ushort* p, f32x4 v) {
  u16x4 o;
#pragma unroll
  for (int j = 0; j < 4; ++j) o[j] = f2bf(v[j]);
  *(u16x4*)p = o;
}

// ---------------- K0: W2 -> 32x32 A-frags; zero deg; b2 flag; ws counter ----------------
// A-frag convention (self-consistent with B; 32-wide analog of verified 16-wide):
//   lane l holds A[row = l&31][k = 16*kt + 8*(l>>5) + j]
constexpr int PREP_DEGB = (NN + 63) / 64;      // 157
__global__ __launch_bounds__(64) void prep_w2(const float* __restrict__ w2,
                                              short8* __restrict__ w2bf,
                                              int* __restrict__ deg,
                                              const float* __restrict__ b2,
                                              float* __restrict__ flag,
                                              int* __restrict__ wsctr) {
  int b = blockIdx.x;
  int lane = threadIdx.x;
  if (b < 72) {                // 72 = 18 jt32 * 4 kt
    int jt = b >> 2, kt = b & 3;
    int hi = lane >> 5, cc = lane & 31;
    short8 v;
#pragma unroll
    for (int j = 0; j < 8; ++j)
      v[j] = (short)f2bf(w2[(size_t)(kt * 16 + 8 * hi + j) * 576 + jt * 32 + cc]);
    w2bf[(size_t)b * 64 + lane] = v;
  } else if (b < 72 + PREP_DEGB) {
    int idx = (b - 72) * 64 + lane;
    if (idx < NN) deg[idx] = 0;
  } else {                     // last block: flag = max|b2|; zero steal counter
    float m = 0.f;
    for (int i = lane; i < 576; i += 64) m = fmaxf(m, fabsf(b2[i]));
#pragma unroll
    for (int off = 1; off < 64; off <<= 1) m = fmaxf(m, __shfl_xor(m, off));
    if (lane == 0) *flag = m;
    if (lane == 1) *wsctr = 0;
  }
}

// ---------------- K2: FUSED mlp1+conv, 32x32 MFMA, 32-edge tiles ----------------
constexpr int CSTR = 68;
constexpr unsigned SM_W2 = 4608 * 16;                       // 73728
constexpr unsigned SM_B2 = 576 * 4;                         // 2304
constexpr unsigned SM_W1 = 512 * 16;                        // 8192
constexpr unsigned SM_B1 = 64 * 4;                          // 256
constexpr unsigned SM_SCR = 8 * 32 * CSTR * 4;              // 69632 (hl aliases this)
constexpr unsigned SM_TOTAL = SM_W2 + SM_B2 + SM_W1 + SM_B1 + SM_SCR;  // 154112

__global__ __launch_bounds__(512) void conv_kernel(
    const float* __restrict__ ef, const float* __restrict__ w1,
    const float* __restrict__ b1, const short8* __restrict__ w2bf,
    const float* __restrict__ b2, const float* __restrict__ nf,
    const float* __restrict__ sh, const int* __restrict__ ei,
    const int* __restrict__ perm, float* __restrict__ efout, int do_copy,
    ushort* __restrict__ tp, const float* __restrict__ flagp,
    int* __restrict__ wsctr)
{
  extern __shared__ char smem[];
  short8* w2lds = (short8*)smem;
  float*  b2lds = (float*)(smem + SM_W2);
  short8* w1f   = (short8*)(smem + SM_W2 + SM_B2);
  float*  b1lds = (float*)(smem + SM_W2 + SM_B2 + SM_W1);
  float*  scrall = (float*)(smem + SM_W2 + SM_B2 + SM_W1 + SM_B1);

  const int tid = threadIdx.x;
  for (int i = tid; i < 4608; i += 512) w2lds[i] = w2bf[i];
  for (int i = tid; i < 576; i += 512) b2lds[i] = b2[i];
  {  // W1 -> 32x32 A-frags: frag = ft*4+kt; lane holds W1T[row=l&31+32ft][k=16kt+8hi+j]
    int frag = tid >> 6, l = tid & 63;
    int ft = frag >> 2, kt = frag & 3;
    int hi = l >> 5, cc = l & 31;
    short8 v;
#pragma unroll
    for (int j = 0; j < 8; ++j)
      v[j] = (short)f2bf(w1[(size_t)(kt * 16 + 8 * hi + j) * 64 + ft * 32 + cc]);
    w1f[tid] = v;
  }
  if (tid < 64) b1lds[tid] = b1[tid];
  const bool nob2 = (*flagp == 0.f);
  __syncthreads();

  const int lane = tid & 63, wid = tid >> 6;
  const int hi = lane >> 5, e32 = lane & 31;
  float* scr = scrall + wid * (32 * CSTR);
  ushort* hl = (ushort*)scr;            // aliases scr (disjoint phases, fenced)

  for (;;) {
    int t;
    if (lane == 0) t = atomicAdd(wsctr, 1);
    t = __shfl(t, 0);
    if (t >= NT32) break;
    const int myeg = t * 32 + e32;

    // ---- phase 0: gather loads (2 lanes per edge; half = hi, 20 floats each)
    const float* __restrict__ src = nf + (size_t)ei[myeg] * 40;
    const f32x4 sv = *(const f32x4*)(sh + (size_t)myeg * 4);
    f32x4 sg0, sg1, sg2, sg3, sg4;
    {
      const float* sp = src + hi * 20;
      sg0 = *(const f32x4*)(sp);
      sg1 = *(const f32x4*)(sp + 4);
      sg2 = *(const f32x4*)(sp + 8);
      sg3 = *(const f32x4*)(sp + 12);
      sg4 = *(const f32x4*)(sp + 16);
    }

    // ---- phase 1: MLP1 GEMM (B-frags from ef; lane col = e32)
    const float* __restrict__ rowp = ef + (size_t)myeg * 64;
    short8 af[4];
#pragma unroll
    for (int kt = 0; kt < 4; ++kt) {
      f32x4 lo = *(const f32x4*)(rowp + kt * 16 + 8 * hi);
      f32x4 hv = *(const f32x4*)(rowp + kt * 16 + 8 * hi + 4);
      if (do_copy) {
        float* q = efout + (size_t)myeg * 64 + kt * 16 + 8 * hi;
        *(f32x4*)q = lo; *(f32x4*)(q + 4) = hv;
      }
      short8 v;
#pragma unroll
      for (int j = 0; j < 4; ++j) { v[j] = (short)f2bf(lo[j]); v[4 + j] = (short)f2bf(hv[j]); }
      af[kt] = v;
    }
    f32x16 hacc0, hacc1;
    {  // init with b1 (row f = ft*32 + 4hi + 8q + j)
#pragma unroll
      for (int q = 0; q < 4; ++q) {
        f32x4 b0 = *(const f32x4*)&b1lds[4 * hi + 8 * q];
        f32x4 b1v = *(const f32x4*)&b1lds[32 + 4 * hi + 8 * q];
#pragma unroll
        for (int j = 0; j < 4; ++j) { hacc0[q * 4 + j] = b0[j]; hacc1[q * 4 + j] = b1v[j]; }
      }
    }
#pragma unroll
    for (int kt = 0; kt < 4; ++kt) {
      hacc0 = mfma32(w1f[(0 * 4 + kt) * 64 + lane], af[kt], hacc0);
      hacc1 = mfma32(w1f[(1 * 4 + kt) * 64 + lane], af[kt], hacc1);
    }

    // ---- phase 2: relu + transpose via hl (stride 72 ushort, 16B-aligned reads)
#pragma unroll
    for (int q = 0; q < 4; ++q) {
      u16x4 o0, o1;
#pragma unroll
      for (int j = 0; j < 4; ++j) {
        o0[j] = f2bf(fmaxf(hacc0[q * 4 + j], 0.f));
        o1[j] = f2bf(fmaxf(hacc1[q * 4 + j], 0.f));
      }
      *(u16x4*)&hl[e32 * 72 + 4 * hi + 8 * q] = o0;
      *(u16x4*)&hl[e32 * 72 + 32 + 4 * hi + 8 * q] = o1;
    }
    asm volatile("" ::: "memory");
    short8 hB[4];
#pragma unroll
    for (int kt = 0; kt < 4; ++kt)
      hB[kt] = *(const short8*)&hl[e32 * 72 + kt * 16 + 8 * hi];
    asm volatile("" ::: "memory");

    // ---- phase 3: coefficient table (raw then a0/a1; in-wave ordered)
    float* ce = scr + e32 * CSTR;
    if (hi == 0) {  // x0[0..15] -> [24..39]; x1 flat 0..3 -> [40..43]
      *(f32x4*)(ce + 24) = sg0; *(f32x4*)(ce + 28) = sg1;
      *(f32x4*)(ce + 32) = sg2; *(f32x4*)(ce + 36) = sg3;
      *(f32x4*)(ce + 40) = sg4;
    } else {        // x1 flat 4..23 -> [44..63]
      *(f32x4*)(ce + 44) = sg0; *(f32x4*)(ce + 48) = sg1;
      *(f32x4*)(ce + 52) = sg2; *(f32x4*)(ce + 56) = sg3;
      *(f32x4*)(ce + 60) = sg4;
    }
    {
      f32x4 r0 = *(const f32x4*)(ce + 24 + 8 * hi);
      f32x4 r1 = *(const f32x4*)(ce + 28 + 8 * hi);
      f32x4 a0, a1;
#pragma unroll
      for (int j = 0; j < 4; ++j) { a0[j] = sv[0] * r0[j]; a1[j] = sv[0] * r1[j]; }
      *(f32x4*)(ce + 8 * hi) = a0;
      *(f32x4*)(ce + 8 * hi + 4) = a1;
      f32x4 av;
#pragma unroll
      for (int uu = 0; uu < 4; ++uu) {
        int u = 4 * hi + uu;
        av[uu] = INV3 * (ce[40 + 3 * u] * sv[1] + ce[41 + 3 * u] * sv[2] +
                         ce[42 + 3 * u] * sv[3]);
      }
      *(f32x4*)(ce + 16 + 4 * hi) = av;
    }
    const float* __restrict__ cc = scr + e32 * CSTR;

    // ---- phase 4: j-GEMM (18 jt32) + lane-local TP; D row=(reg&3)+8(reg>>2)+4hi
    f32x4 oa = {0.f, 0.f, 0.f, 0.f}, ob = {0.f, 0.f, 0.f, 0.f};
    f32x4 c0 = {0.f, 0.f, 0.f, 0.f};
    f32x4 c1[3] = {};

#pragma unroll
    for (int jt = 0; jt < 8; ++jt) {           // w00: u = jt*2 + (reg>>3)
      f32x16 d = {};
      if (!nob2) {
#pragma unroll
        for (int q = 0; q < 4; ++q) {
          f32x4 bv = *(const f32x4*)&b2lds[jt * 32 + 4 * hi + 8 * q];
#pragma unroll
          for (int j = 0; j < 4; ++j) d[q * 4 + j] = bv[j];
        }
      }
#pragma unroll
      for (int kt = 0; kt < 4; ++kt) d = mfma32(w2lds[(jt * 4 + kt) * 64 + lane], hB[kt], d);
      const float au0 = cc[jt * 2], au1 = cc[jt * 2 + 1];
#pragma unroll
      for (int r = 0; r < 16; ++r) {
        float v = ((r & 8) ? au1 : au0) * d[r];
        if (r & 4) ob[r & 3] += v; else oa[r & 3] += v;
      }
    }
#pragma unroll
    for (int jt = 8; jt < 12; ++jt) {          // w11: u = (jt-8)*2 + (reg>>3)
      f32x16 d = {};
      if (!nob2) {
#pragma unroll
        for (int q = 0; q < 4; ++q) {
          f32x4 bv = *(const f32x4*)&b2lds[jt * 32 + 4 * hi + 8 * q];
#pragma unroll
          for (int j = 0; j < 4; ++j) d[q * 4 + j] = bv[j];
        }
      }
#pragma unroll
      for (int kt = 0; kt < 4; ++kt) d = mfma32(w2lds[(jt * 4 + kt) * 64 + lane], hB[kt], d);
      const float au0 = cc[16 + (jt - 8) * 2], au1 = cc[16 + (jt - 8) * 2 + 1];
#pragma unroll
      for (int r = 0; r < 16; ++r) {
        float v = ((r & 8) ? au1 : au0) * d[r];
        if (r & 4) ob[r & 3] += v; else oa[r & 3] += v;
      }
    }
#pragma unroll
    for (int jt = 12; jt < 16; ++jt) {         // w01: u = (jt-12)*4 + (reg>>2)
      f32x16 d = {};
      if (!nob2) {
#pragma unroll
        for (int q = 0; q < 4; ++q) {
          f32x4 bv = *(const f32x4*)&b2lds[jt * 32 + 4 * hi + 8 * q];
#pragma unroll
          for (int j = 0; j < 4; ++j) d[q * 4 + j] = bv[j];
        }
      }
#pragma unroll
      for (int kt = 0; kt < 4; ++kt) d = mfma32(w2lds[(jt * 4 + kt) * 64 + lane], hB[kt], d);
      const f32x4 x4 = *(const f32x4*)&cc[24 + (jt - 12) * 4];
#pragma unroll
      for (int r = 0; r < 16; ++r) c0[r & 3] += x4[r >> 2] * d[r];
    }
#pragma unroll
    for (int jt = 16; jt < 18; ++jt) {         // w10: u = (jt-16)*4 + (reg>>2)
      f32x16 d = {};
      if (!nob2) {
#pragma unroll
        for (int q = 0; q < 4; ++q) {
          f32x4 bv = *(const f32x4*)&b2lds[jt * 32 + 4 * hi + 8 * q];
#pragma unroll
          for (int j = 0; j < 4; ++j) d[q * 4 + j] = bv[j];
        }
      }
#pragma unroll
      for (int kt = 0; kt < 4; ++kt) d = mfma32(w2lds[(jt * 4 + kt) * 64 + lane], hB[kt], d);
      const f32x4 xA = *(const f32x4*)&cc[40 + 12 * (jt - 16)];
      const f32x4 xB = *(const f32x4*)&cc[44 + 12 * (jt - 16)];
      const f32x4 xC = *(const f32x4*)&cc[48 + 12 * (jt - 16)];
#pragma unroll
      for (int r = 0; r < 16; ++r) {
        const int q = r >> 2;
#pragma unroll
        for (int i = 0; i < 3; ++i) {
          const int fl = 3 * q + i;
          float x = (fl < 4) ? xA[fl] : (fl < 8) ? xB[fl - 4] : xC[fl - 8];
          c1[i][r & 3] += x * d[r];
        }
      }
    }

    // ---- store: edge row covered exactly by its two hi-lanes (no folds)
    ushort* tpr = tp + (size_t)perm[myeg] * TPSTR;
    f32x4 s;
#pragma unroll
    for (int j = 0; j < 4; ++j) s[j] = ALPHA * oa[j];
    st4u(tpr + 4 * hi, s);
#pragma unroll
    for (int j = 0; j < 4; ++j) s[j] = ALPHA * ob[j];
    st4u(tpr + 8 + 4 * hi, s);
    float wv[12];
#pragma unroll
    for (int q = 0; q < 4; ++q)
#pragma unroll
      for (int i = 0; i < 3; ++i)
        wv[q * 3 + i] = ALPHA * (sv[1 + i] * c0[q] + sv[0] * c1[i][q]);
#pragma unroll
    for (int p = 0; p < 3; ++p) {
      f32x4 v = {wv[4 * p], wv[4 * p + 1], wv[4 * p + 2], wv[4 * p + 3]};
      st4u(tpr + 16 + 12 * hi + 4 * p, v);
    }
  }
}

// ---------------- CSR build ----------------
__global__ __launch_bounds__(256) void hist_kernel(const int* __restrict__ ei,
                                                   int* __restrict__ deg) {
  for (int e = blockIdx.x * 256 + threadIdx.x; e < NE; e += gridDim.x * 256)
    atomicAdd(&deg[ei[NE + e]], 1);
}

__global__ __launch_bounds__(1024) void scan_kernel(const int* __restrict__ deg,
                                                    int* __restrict__ rowoff,
                                                    int* __restrict__ wcur) {
  __shared__ int wsum[16];
  const int t = threadIdx.x;
  const int lane = t & 63, wid = t >> 6;
  const int base = t * 10;
  int d[10];
  int sum = 0;
#pragma unroll
  for (int j = 0; j < 10; ++j) {
    int n = base + j;
    d[j] = (n < NN) ? deg[n] : 0;
    sum += d[j];
  }
  int val = sum;
#pragma unroll
  for (int off = 1; off < 64; off <<= 1) {
    int v = __shfl_up(val, off);
    if (lane >= off) val += v;
  }
  if (lane == 63) wsum[wid] = val;
  __syncthreads();
  if (t < 16) {
    int v = wsum[t];
#pragma unroll
    for (int off = 1; off < 16; off <<= 1) {
      int u = __shfl_up(v, off);
      if (t >= off) v += u;
    }
    wsum[t] = v;
  }
  __syncthreads();
  const int waveoff = (wid > 0) ? wsum[wid - 1] : 0;
  int run = waveoff + (val - sum);
#pragma unroll
  for (int j = 0; j < 10; ++j) {
    int n = base + j;
    if (n < NN) { rowoff[n] = run; wcur[n] = run; }
    run += d[j];
  }
  if (t == 1023) rowoff[NN] = run;
}

__global__ __launch_bounds__(256) void fill_kernel(const int* __restrict__ ei,
                                                   int* __restrict__ wcur,
                                                   int* __restrict__ perm) {
  for (int e = blockIdx.x * 256 + threadIdx.x; e < NE; e += gridDim.x * 256) {
    int pos = atomicAdd(&wcur[ei[NE + e]], 1);
    perm[e] = pos;
  }
}

// ---------------- gather: linear CSR bf16 rows; per-block pstats ----------------
__global__ __launch_bounds__(256) void gather_kernel(
    const ushort* __restrict__ tp, const int* __restrict__ rowoff,
    const float* __restrict__ nf, float* __restrict__ pre,
    float* __restrict__ pstats)
{
  __shared__ float ls[40];
  const int tid = threadIdx.x;
  if (tid < 40) ls[tid] = 0.f;
  __syncthreads();
  const int wid = tid >> 6, lane = tid & 63;
  float sacc = 0.f, qacc = 0.f;
  if (lane < 40) {
#pragma unroll 1
    for (int i = 0; i < 4; ++i) {
      const int n = blockIdx.x * 16 + wid * 4 + i;
      const int r0 = rowoff[n], r1 = rowoff[n + 1];
      float s0 = 0.f, s1 = 0.f, s2 = 0.f, s3 = 0.f,
            s4 = 0.f, s5 = 0.f, s6 = 0.f, s7 = 0.f;
      int k = r0;
      for (; k + 8 <= r1; k += 8) {
        s0 += bf2f(tp[(size_t)(k + 0) * TPSTR + lane]);
        s1 += bf2f(tp[(size_t)(k + 1) * TPSTR + lane]);
        s2 += bf2f(tp[(size_t)(k + 2) * TPSTR + lane]);
        s3 += bf2f(tp[(size_t)(k + 3) * TPSTR + lane]);
        s4 += bf2f(tp[(size_t)(k + 4) * TPSTR + lane]);
        s5 += bf2f(tp[(size_t)(k + 5) * TPSTR + lane]);
        s6 += bf2f(tp[(size_t)(k + 6) * TPSTR + lane]);
        s7 += bf2f(tp[(size_t)(k + 7) * TPSTR + lane]);
      }
      for (; k < r1; ++k) s0 += bf2f(tp[(size_t)k * TPSTR + lane]);
      float s = ((s0 + s1) + (s2 + s3)) + ((s4 + s5) + (s6 + s7));
      float val = s / fmaxf((float)(r1 - r0), 1.f) + nf[(size_t)n * 40 + lane];
      pre[(size_t)n * 40 + lane] = val;
      if (lane < 16) { sacc += val; qacc += val * val; }
      else qacc += val * val;
    }
    if (lane < 16) {
      atomicAdd(&ls[lane], sacc);
      atomicAdd(&ls[16 + lane], qacc);
    } else {
      atomicAdd(&ls[32 + (lane - 16) / 3], qacc);
    }
  }
  __syncthreads();
  if (tid < 40) pstats[(size_t)blockIdx.x * 40 + tid] = ls[tid];
}

__global__ __launch_bounds__(256) void stats_reduce(
    const float* __restrict__ pstats, float* __restrict__ stats)
{
  const int c = blockIdx.x;
  float s = 0.f;
  for (int i = threadIdx.x; i < GBLK; i += 256) s += pstats[(size_t)i * 40 + c];
#pragma unroll
  for (int off = 1; off < 64; off <<= 1) s += __shfl_xor(s, off);
  __shared__ float red[4];
  if ((threadIdx.x & 63) == 0) red[threadIdx.x >> 6] = s;
  __syncthreads();
  if (threadIdx.x == 0) stats[c] = (red[0] + red[1]) + (red[2] + red[3]);
}

__global__ __launch_bounds__(256) void node_pass2(
    const float* __restrict__ pre, const float* __restrict__ stats,
    const float* __restrict__ bnws, const float* __restrict__ bnbs,
    const float* __restrict__ bnwv, float* __restrict__ out)
{
  int idx = blockIdx.x * blockDim.x + threadIdx.x;
  if (idx >= NN * 40) return;
  int n = idx / 40;
  int c = idx - n * 40;
  float val = pre[idx];
  constexpr float invN = 1.0f / NN;
  if (c < 16) {
    float mu = stats[c] * invN;
    float var = stats[16 + c] * invN - mu * mu;
    out[idx] = (val - mu) * (rsqrtf(var + EPSV) * bnws[c]) + bnbs[c];
  } else {
    int u = (c - 16) / 3;
    float vn = stats[32 + u] * (invN / 3.0f);
    out[idx] = val * (rsqrtf(vn + EPSV) * bnwv[u]);
  }
}

__global__ __launch_bounds__(256) void copy_ef(const f32x4* __restrict__ src,
                                               f32x4* __restrict__ dst) {
  const int n4 = NE * 64 / 4;
  for (int i = blockIdx.x * blockDim.x + threadIdx.x; i < n4;
       i += gridDim.x * blockDim.x)
    dst[i] = src[i];
}

extern "C" void kernel_launch(void* const* d_in, const int* in_sizes, int n_in,
                              void* d_out, int out_size, void* d_ws, size_t ws_size,
                              hipStream_t stream) {
  (void)in_sizes; (void)n_in; (void)out_size;
  const float* nf   = (const float*)d_in[0];
  const float* ef   = (const float*)d_in[1];
  const float* sh   = (const float*)d_in[2];
  const int*   ei   = (const int*)d_in[3];
  const float* w1   = (const float*)d_in[4];
  const float* b1   = (const float*)d_in[5];
  const float* w2   = (const float*)d_in[6];
  const float* b2   = (const float*)d_in[7];
  const float* bnws = (const float*)d_in[8];
  const float* bnbs = (const float*)d_in[9];
  const float* bnwv = (const float*)d_in[10];

  float* out = (float*)d_out;
  float* efout = out + (size_t)NN * 40;

  // ws layout
  char* w = (char*)d_ws;
  int* deg     = (int*)w;                               // NN (zeroed by prep_w2)
  float* stats = (float*)(w + (size_t)NN * 4);          // 40; [44]=flag; [45]=steal ctr
  float* flag  = stats + 44;
  int* wsctr   = (int*)(stats + 45);
  int* rowoff  = (int*)(w + (size_t)NN * 4 + 192);      // NN+1
  int* wcur    = rowoff + NN + 1;
  int* perm    = wcur + NN;                             // NE
  float* pre   = (float*)(perm + NE);                   // NN*40
  float* pstats = pre + (size_t)NN * 40;                // GBLK*40
  size_t base  = ((size_t)((char*)(pstats + (size_t)GBLK * 40) - w) + 255) & ~(size_t)255;
  short8* w2bf = (short8*)(w + base);                   // 73728 B
  size_t tpoff = (base + SM_W2 + 255) & ~(size_t)255;

  const size_t TPB = (size_t)NE * TPSTR * 2;            // 20.48 MB
  const size_t needA = tpoff + TPB;

  hipFuncSetAttribute((const void*)conv_kernel,
                      hipFuncAttributeMaxDynamicSharedMemorySize, SM_TOTAL);

  prep_w2<<<72 + PREP_DEGB + 1, 64, 0, stream>>>(w2, w2bf, deg, b2, flag, wsctr);

  const int pblocks = (NN * 40 + 255) / 256;

  hist_kernel<<<625, 256, 0, stream>>>(ei, deg);
  scan_kernel<<<1, 1024, 0, stream>>>(deg, rowoff, wcur);
  fill_kernel<<<625, 256, 0, stream>>>(ei, wcur, perm);

  if (ws_size >= needA) {            // Plan A: tp in ws; ef copy fused in conv
    ushort* tp = (ushort*)(w + tpoff);
    conv_kernel<<<256, 512, SM_TOTAL, stream>>>(
        ef, w1, b1, w2bf, b2, nf, sh, ei, perm, efout, 1, tp, flag, wsctr);
    gather_kernel<<<GBLK, 256, 0, stream>>>(tp, rowoff, nf, pre, pstats);
    stats_reduce<<<40, 256, 0, stream>>>(pstats, stats);
    node_pass2<<<pblocks, 256, 0, stream>>>(pre, stats, bnws, bnbs, bnwv, out);
  } else {                           // Plan D: tp in efout region; copy ef last
    ushort* tp = (ushort*)efout;
    conv_kernel<<<256, 512, SM_TOTAL, stream>>>(
        ef, w1, b1, w2bf, b2, nf, sh, ei, perm, efout, 0, tp, flag, wsctr);
    gather_kernel<<<GBLK, 256, 0, stream>>>(tp, rowoff, nf, pre, pstats);
    stats_reduce<<<40, 256, 0, stream>>>(pstats, stats);
    node_pass2<<<pblocks, 256, 0, stream>>>(pre, stats, bnws, bnbs, bnwv, out);
    copy_ef<<<2048, 256, 0, stream>>>((const f32x4*)ef, (f32x4*)efout);
  }
}

// Round 21
// 94.490 us; speedup vs baseline: 1.9568x; 1.9568x over previous
//
#include <hip/hip_runtime.h>

typedef __attribute__((ext_vector_type(8))) short short8;
typedef __attribute__((ext_vector_type(4))) float f32x4;
typedef __attribute__((ext_vector_type(4))) ushort u16x4;

constexpr int NN = 10000;
constexpr int NE = 160000;
constexpr int NT = NE / 16;                    // 10000 edge-tiles
constexpr int TPSTR = 64;                      // tp row stride in USHORT (128 B = 2 lines)
constexpr int GBLK = 625;                      // gather blocks (625*16 = NN)
constexpr float EPSV = 1e-5f;
constexpr float INV3 = 0.57735026918962576f;   // 1/sqrt(3)
constexpr float ALPHA = 0.20412414523193152f;  // 1/sqrt(16+8)

__device__ __forceinline__ ushort f2bf(float x) {
  unsigned u = __float_as_uint(x);
  u += 0x7fffu + ((u >> 16) & 1u);
  return (ushort)(u >> 16);
}
__device__ __forceinline__ float bf2f(ushort u) {
  return __uint_as_float(((unsigned)u) << 16);
}
__device__ __forceinline__ f32x4 mfma16(short8 a, short8 b, f32x4 c) {
  return __builtin_amdgcn_mfma_f32_16x16x32_bf16(a, b, c, 0, 0, 0);
}
__device__ __forceinline__ void st4u(ushort* p, f32x4 v) {
  u16x4 o;
#pragma unroll
  for (int j = 0; j < 4; ++j) o[j] = f2bf(v[j]);
  *(u16x4*)p = o;
}

// ---------------- K0: W2 -> bf16 A-frags; zero deg; b2 |max| flag ----------------
constexpr int PREP_DEGB = (NN + 63) / 64;      // 157
__global__ __launch_bounds__(64) void prep_w2(const float* __restrict__ w2,
                                              short8* __restrict__ w2bf,
                                              int* __restrict__ deg,
                                              const float* __restrict__ b2,
                                              float* __restrict__ flag) {
  int b = blockIdx.x;
  int lane = threadIdx.x;
  if (b < 72) {                // 72 = 36 jt * 2 kc
    int jt = b >> 1, kc = b & 1;
    int g = lane >> 4, c = lane & 15;
    short8 v;
#pragma unroll
    for (int j = 0; j < 8; ++j)
      v[j] = (short)f2bf(w2[(kc * 32 + 8 * g + j) * 576 + jt * 16 + c]);
    w2bf[(jt * 2 + kc) * 64 + lane] = v;
  } else if (b < 72 + PREP_DEGB) {
    int idx = (b - 72) * 64 + lane;
    if (idx < NN) deg[idx] = 0;
  } else {                     // last block: flag = max|b2|
    float m = 0.f;
    for (int i = lane; i < 576; i += 64) m = fmaxf(m, fabsf(b2[i]));
#pragma unroll
    for (int off = 1; off < 64; off <<= 1) m = fmaxf(m, __shfl_xor(m, off));
    if (lane == 0) *flag = m;
  }
}

// ---------------- K2: FUSED mlp1+conv (r18 proven body; bf16 tp out) ----------------
// 32x32-MFMA variant (r20) spilled (f32x16 accs); 96-VGPR 16x16 body is the
// allocator's stable point -- do NOT add live state.
constexpr int CSTR = 68;
constexpr unsigned SM_W2 = 4608 * 16;                       // 73728 B
constexpr unsigned SM_B2 = 576 * 4;                         // 2304 B
constexpr unsigned SM_W1 = 512 * 16;                        // 8192 B
constexpr unsigned SM_B1 = 64 * 4;                          // 256 B
constexpr unsigned SM_HL = 8 * 16 * 72 * 2;                 // 18432 B (transpose)
constexpr unsigned SM_SCR = 8 * 16 * CSTR * 4;              // 34816 B
constexpr unsigned SM_TOTAL = SM_W2 + SM_B2 + SM_W1 + SM_B1 + SM_HL + SM_SCR; // 137728

__global__ __launch_bounds__(512) void conv_kernel(
    const float* __restrict__ ef, const float* __restrict__ w1,
    const float* __restrict__ b1, const short8* __restrict__ w2bf,
    const float* __restrict__ b2, const float* __restrict__ nf,
    const float* __restrict__ sh, const int* __restrict__ ei,
    const int* __restrict__ perm, float* __restrict__ efout, int do_copy,
    ushort* __restrict__ tp, const float* __restrict__ flagp)
{
  extern __shared__ char smem[];
  short8* w2lds = (short8*)smem;
  float*  b2lds = (float*)(smem + SM_W2);
  short8* w1f   = (short8*)(smem + SM_W2 + SM_B2);
  float*  b1lds = (float*)(smem + SM_W2 + SM_B2 + SM_W1);
  ushort* hlall = (ushort*)(smem + SM_W2 + SM_B2 + SM_W1 + SM_B1);
  float*  scrall = (float*)(smem + SM_W2 + SM_B2 + SM_W1 + SM_B1 + SM_HL);

  const int tid = threadIdx.x;
  for (int i = tid; i < 4608; i += 512) w2lds[i] = w2bf[i];
  for (int i = tid; i < 576; i += 512) b2lds[i] = b2[i];
  {  // W1 -> bf16 B-frags, one per thread (512 frags)
    int tile = tid >> 6, l = tid & 63;
    int nt = tile >> 1, kc = tile & 1;
    int gg = l >> 4, cc = l & 15;
    short8 v;
#pragma unroll
    for (int j = 0; j < 8; ++j)
      v[j] = (short)f2bf(w1[(kc * 32 + 8 * gg + j) * 64 + nt * 16 + cc]);
    w1f[tid] = v;
  }
  if (tid < 64) b1lds[tid] = b1[tid];
  const bool nob2 = (*flagp == 0.f);   // uniform
  __syncthreads();

  const int lane = tid & 63, wid = tid >> 6;
  const int g = lane >> 4, c = lane & 15;
  const int gh = g >> 1;
  const int e = lane >> 2, part = lane & 3;
  float* scr = scrall + wid * (16 * CSTR);
  ushort* hl = hlall + wid * (16 * 72);

  for (int t = blockIdx.x * 8 + wid; t < NT; t += gridDim.x * 8) {
    // ---- phase 0: issue gather loads early (latency hides under MLP1)
    const int ege = t * 16 + e;
    const float* __restrict__ src = nf + (size_t)ei[ege] * 40;
    const f32x4 sv = *(const f32x4*)(sh + (size_t)ege * 4);
    const f32x4 v0 = *(const f32x4*)(src + part * 4);
    const f32x4 v1 = *(const f32x4*)(src + 16 + part * 4);
    f32x4 v2 = {};
    if (part < 2) v2 = *(const f32x4*)(src + 32 + part * 4);

    // ---- phase 1: MLP1 GEMM (lane c = edge of this tile)
    const long ebase = (long)t * 16;
    short8 af[2];
    const float* rowp = ef + (ebase + c) * 64;
#pragma unroll
    for (int kc = 0; kc < 2; ++kc) {
      const f32x4* p = (const f32x4*)(rowp + kc * 32 + 8 * g);
      f32x4 lo = p[0], hi = p[1];
      if (do_copy) {
        f32x4* q = (f32x4*)(efout + (ebase + c) * 64 + kc * 32 + 8 * g);
        q[0] = lo; q[1] = hi;
      }
      short8 v;
#pragma unroll
      for (int j = 0; j < 4; ++j) { v[j] = (short)f2bf(lo[j]); v[4 + j] = (short)f2bf(hi[j]); }
      af[kc] = v;
    }
    f32x4 hacc[4] = {};
#pragma unroll
    for (int nt = 0; nt < 4; ++nt)
#pragma unroll
      for (int kc = 0; kc < 2; ++kc)
        hacc[nt] = mfma16(af[kc], w1f[(nt * 2 + kc) * 64 + lane], hacc[nt]);

    // ---- phase 2: bias+relu, per-wave LDS transpose -> h0/h1 (in-wave ordered)
#pragma unroll
    for (int nt = 0; nt < 4; ++nt) {
      float bv = b1lds[nt * 16 + c];
#pragma unroll
      for (int q = 0; q < 4; ++q) {
        float h = fmaxf(hacc[nt][q] + bv, 0.f);
        hl[(4 * g + q) * 72 + nt * 16 + c] = f2bf(h);
      }
    }
    const short8 h0 = *(const short8*)&hl[c * 72 + 8 * g];
    const short8 h1 = *(const short8*)&hl[c * 72 + 32 + 8 * g];

    // ---- phase 3: coefficient table from phase-0 regs (4 lanes per edge)
    {
      float* ce = scr + e * CSTR;
      f32x4 a0;
#pragma unroll
      for (int q = 0; q < 4; ++q) a0[q] = sv[0] * v0[q];
      *(f32x4*)(ce + 4 * part) = a0;
      *(f32x4*)(ce + 24 + 4 * part) = v0;
      *(f32x4*)(ce + 40 + 4 * part) = v1;
      if (part < 2) *(f32x4*)(ce + 56 + 4 * part) = v2;
#pragma unroll
      for (int uu = 0; uu < 2; ++uu) {
        int u = 2 * part + uu;
        ce[16 + u] = INV3 * (ce[40 + 3 * u] * sv[1] + ce[41 + 3 * u] * sv[2] +
                             ce[42 + 3 * u] * sv[3]);
      }
    }
    const float* __restrict__ cc = scr + c * CSTR;

    // ---- phase 4: j-GEMM + lane-local tensor product
    f32x4 out0acc = {0.f, 0.f, 0.f, 0.f};
    f32x4 c0acc = {0.f, 0.f, 0.f, 0.f};
    f32x4 c1acc[3] = {};

    if (nob2) {  // FAST PATH: zero-init d, independent d0/d1 chains
#pragma unroll
      for (int j4 = 0; j4 < 4; ++j4) {         // w00: u=jt, cc[0..15] vectorized
        const f32x4 a4 = *(const f32x4*)&cc[j4 * 4];
#pragma unroll
        for (int jj = 0; jj < 4; ++jj) {
          const int jt = j4 * 4 + jj;
          f32x4 z = {0.f, 0.f, 0.f, 0.f};
          f32x4 d0 = mfma16(w2lds[(jt * 2 + 0) * 64 + lane], h0, z);
          f32x4 d1 = mfma16(w2lds[(jt * 2 + 1) * 64 + lane], h1, z);
          float a = a4[jj];
#pragma unroll
          for (int q = 0; q < 4; ++q) {
            out0acc[q] = fmaf(a, d0[q], out0acc[q]);
            out0acc[q] = fmaf(a, d1[q], out0acc[q]);
          }
        }
      }
#pragma unroll
      for (int j4 = 0; j4 < 2; ++j4) {         // w11: u=jt-16, cc[16..23] vectorized
        const f32x4 a4 = *(const f32x4*)&cc[16 + j4 * 4];
#pragma unroll
        for (int jj = 0; jj < 4; ++jj) {
          const int jt = 16 + j4 * 4 + jj;
          f32x4 z = {0.f, 0.f, 0.f, 0.f};
          f32x4 d0 = mfma16(w2lds[(jt * 2 + 0) * 64 + lane], h0, z);
          f32x4 d1 = mfma16(w2lds[(jt * 2 + 1) * 64 + lane], h1, z);
          float a = a4[jj];
#pragma unroll
          for (int q = 0; q < 4; ++q) {
            out0acc[q] = fmaf(a, d0[q], out0acc[q]);
            out0acc[q] = fmaf(a, d1[q], out0acc[q]);
          }
        }
      }
#pragma unroll
      for (int jt = 24; jt < 32; ++jt) {       // w01: u=2(jt-24)+gh
        f32x4 z = {0.f, 0.f, 0.f, 0.f};
        f32x4 d0 = mfma16(w2lds[(jt * 2 + 0) * 64 + lane], h0, z);
        f32x4 d1 = mfma16(w2lds[(jt * 2 + 1) * 64 + lane], h1, z);
        float a = cc[24 + 2 * (jt - 24) + gh];
#pragma unroll
        for (int q = 0; q < 4; ++q) {
          c0acc[q] = fmaf(a, d0[q], c0acc[q]);
          c0acc[q] = fmaf(a, d1[q], c0acc[q]);
        }
      }
#pragma unroll
      for (int jt = 32; jt < 36; ++jt) {       // w10: u=2(jt-32)+gh
        f32x4 z = {0.f, 0.f, 0.f, 0.f};
        f32x4 d0 = mfma16(w2lds[(jt * 2 + 0) * 64 + lane], h0, z);
        f32x4 d1 = mfma16(w2lds[(jt * 2 + 1) * 64 + lane], h1, z);
        const int ub = 40 + 3 * (2 * (jt - 32) + gh);
#pragma unroll
        for (int i = 0; i < 3; ++i) {
          float a = cc[ub + i];
#pragma unroll
          for (int q = 0; q < 4; ++q) {
            c1acc[i][q] = fmaf(a, d0[q], c1acc[i][q]);
            c1acc[i][q] = fmaf(a, d1[q], c1acc[i][q]);
          }
        }
      }
    } else {     // GENERAL PATH (b2 != 0): bias in C operand
#pragma unroll
      for (int jt = 0; jt < 16; ++jt) {
        f32x4 d = *(const f32x4*)&b2lds[jt * 16 + 4 * g];
        d = mfma16(w2lds[(jt * 2 + 0) * 64 + lane], h0, d);
        d = mfma16(w2lds[(jt * 2 + 1) * 64 + lane], h1, d);
        float a = cc[jt];
#pragma unroll
        for (int q = 0; q < 4; ++q) out0acc[q] = fmaf(a, d[q], out0acc[q]);
      }
#pragma unroll
      for (int jt = 16; jt < 24; ++jt) {
        f32x4 d = *(const f32x4*)&b2lds[jt * 16 + 4 * g];
        d = mfma16(w2lds[(jt * 2 + 0) * 64 + lane], h0, d);
        d = mfma16(w2lds[(jt * 2 + 1) * 64 + lane], h1, d);
        float a = cc[16 + (jt - 16)];
#pragma unroll
        for (int q = 0; q < 4; ++q) out0acc[q] = fmaf(a, d[q], out0acc[q]);
      }
#pragma unroll
      for (int jt = 24; jt < 32; ++jt) {
        f32x4 d = *(const f32x4*)&b2lds[jt * 16 + 4 * g];
        d = mfma16(w2lds[(jt * 2 + 0) * 64 + lane], h0, d);
        d = mfma16(w2lds[(jt * 2 + 1) * 64 + lane], h1, d);
        float a = cc[24 + 2 * (jt - 24) + gh];
#pragma unroll
        for (int q = 0; q < 4; ++q) c0acc[q] = fmaf(a, d[q], c0acc[q]);
      }
#pragma unroll
      for (int jt = 32; jt < 36; ++jt) {
        f32x4 d = *(const f32x4*)&b2lds[jt * 16 + 4 * g];
        d = mfma16(w2lds[(jt * 2 + 0) * 64 + lane], h0, d);
        d = mfma16(w2lds[(jt * 2 + 1) * 64 + lane], h1, d);
        const int ub = 40 + 3 * (2 * (jt - 32) + gh);
#pragma unroll
        for (int i = 0; i < 3; ++i) {
          float a = cc[ub + i];
#pragma unroll
          for (int q = 0; q < 4; ++q) c1acc[i][q] = fmaf(a, d[q], c1acc[i][q]);
        }
      }
    }

    // fold gh halves (lane ^ 32)
#pragma unroll
    for (int q = 0; q < 4; ++q) c0acc[q] += __shfl_xor(c0acc[q], 32);
#pragma unroll
    for (int i = 0; i < 3; ++i)
#pragma unroll
      for (int q = 0; q < 4; ++q) c1acc[i][q] += __shfl_xor(c1acc[i][q], 32);

    // store into this edge's CSR slot (bf16 rows, 128 B line-pair aligned)
    const int eg = t * 16 + c;
    const f32x4 shv = *(const f32x4*)(sh + (size_t)eg * 4);
    ushort* tpr = tp + (size_t)perm[eg] * TPSTR;
    f32x4 o0;
#pragma unroll
    for (int q = 0; q < 4; ++q) o0[q] = ALPHA * out0acc[q];
    st4u(tpr + 4 * g, o0);
    if (g < 2) {
      float wv[12];
#pragma unroll
      for (int q = 0; q < 4; ++q)
#pragma unroll
        for (int i = 0; i < 3; ++i)
          wv[q * 3 + i] = ALPHA * (shv[1 + i] * c0acc[q] + shv[0] * c1acc[i][q]);
#pragma unroll
      for (int p = 0; p < 3; ++p) {
        f32x4 v = {wv[4 * p], wv[4 * p + 1], wv[4 * p + 2], wv[4 * p + 3]};
        st4u(tpr + 16 + 12 * g + 4 * p, v);
      }
    }
  }
}

// ---------------- CSR build ----------------
__global__ __launch_bounds__(256) void hist_kernel(const int* __restrict__ ei,
                                                   int* __restrict__ deg) {
  for (int e = blockIdx.x * 256 + threadIdx.x; e < NE; e += gridDim.x * 256)
    atomicAdd(&deg[ei[NE + e]], 1);
}

// wave-level shfl_up scan, 2 barriers total
__global__ __launch_bounds__(1024) void scan_kernel(const int* __restrict__ deg,
                                                    int* __restrict__ rowoff,
                                                    int* __restrict__ wcur) {
  __shared__ int wsum[16];
  const int t = threadIdx.x;
  const int lane = t & 63, wid = t >> 6;
  const int base = t * 10;
  int d[10];
  int sum = 0;
#pragma unroll
  for (int j = 0; j < 10; ++j) {
    int n = base + j;
    d[j] = (n < NN) ? deg[n] : 0;
    sum += d[j];
  }
  int val = sum;                       // inclusive scan within wave
#pragma unroll
  for (int off = 1; off < 64; off <<= 1) {
    int v = __shfl_up(val, off);
    if (lane >= off) val += v;
  }
  if (lane == 63) wsum[wid] = val;
  __syncthreads();
  if (t < 16) {
    int v = wsum[t];
#pragma unroll
    for (int off = 1; off < 16; off <<= 1) {
      int u = __shfl_up(v, off);
      if (t >= off) v += u;
    }
    wsum[t] = v;                       // inclusive over waves
  }
  __syncthreads();
  const int waveoff = (wid > 0) ? wsum[wid - 1] : 0;
  int run = waveoff + (val - sum);     // exclusive prefix for this thread
#pragma unroll
  for (int j = 0; j < 10; ++j) {
    int n = base + j;
    if (n < NN) { rowoff[n] = run; wcur[n] = run; }
    run += d[j];
  }
  if (t == 1023) rowoff[NN] = run;
}

__global__ __launch_bounds__(256) void fill_kernel(const int* __restrict__ ei,
                                                   int* __restrict__ wcur,
                                                   int* __restrict__ perm) {
  for (int e = blockIdx.x * 256 + threadIdx.x; e < NE; e += gridDim.x * 256) {
    int pos = atomicAdd(&wcur[ei[NE + e]], 1);
    perm[e] = pos;
  }
}

// ---------------- gather: linear CSR bf16 rows; per-block pstats (non-atomic) ----------------
__global__ __launch_bounds__(256) void gather_kernel(
    const ushort* __restrict__ tp, const int* __restrict__ rowoff,
    const float* __restrict__ nf, float* __restrict__ pre,
    float* __restrict__ pstats)
{
  __shared__ float ls[40];
  const int tid = threadIdx.x;
  if (tid < 40) ls[tid] = 0.f;
  __syncthreads();
  const int wid = tid >> 6, lane = tid & 63;
  float sacc = 0.f, qacc = 0.f;
  if (lane < 40) {
#pragma unroll 1
    for (int i = 0; i < 4; ++i) {
      const int n = blockIdx.x * 16 + wid * 4 + i;   // GBLK*16 == NN exactly
      const int r0 = rowoff[n], r1 = rowoff[n + 1];
      float s0 = 0.f, s1 = 0.f, s2 = 0.f, s3 = 0.f,
            s4 = 0.f, s5 = 0.f, s6 = 0.f, s7 = 0.f;
      int k = r0;
      for (; k + 8 <= r1; k += 8) {
        s0 += bf2f(tp[(size_t)(k + 0) * TPSTR + lane]);
        s1 += bf2f(tp[(size_t)(k + 1) * TPSTR + lane]);
        s2 += bf2f(tp[(size_t)(k + 2) * TPSTR + lane]);
        s3 += bf2f(tp[(size_t)(k + 3) * TPSTR + lane]);
        s4 += bf2f(tp[(size_t)(k + 4) * TPSTR + lane]);
        s5 += bf2f(tp[(size_t)(k + 5) * TPSTR + lane]);
        s6 += bf2f(tp[(size_t)(k + 6) * TPSTR + lane]);
        s7 += bf2f(tp[(size_t)(k + 7) * TPSTR + lane]);
      }
      for (; k < r1; ++k) s0 += bf2f(tp[(size_t)k * TPSTR + lane]);
      float s = ((s0 + s1) + (s2 + s3)) + ((s4 + s5) + (s6 + s7));
      float val = s / fmaxf((float)(r1 - r0), 1.f) + nf[(size_t)n * 40 + lane];
      pre[(size_t)n * 40 + lane] = val;
      if (lane < 16) { sacc += val; qacc += val * val; }
      else qacc += val * val;
    }
    if (lane < 16) {
      atomicAdd(&ls[lane], sacc);
      atomicAdd(&ls[16 + lane], qacc);
    } else {
      atomicAdd(&ls[32 + (lane - 16) / 3], qacc);
    }
  }
  __syncthreads();
  if (tid < 40) pstats[(size_t)blockIdx.x * 40 + tid] = ls[tid];
}

// 40 blocks: channel c = blockIdx; sum 625 block-partials
__global__ __launch_bounds__(256) void stats_reduce(
    const float* __restrict__ pstats, float* __restrict__ stats)
{
  const int c = blockIdx.x;
  float s = 0.f;
  for (int i = threadIdx.x; i < GBLK; i += 256) s += pstats[(size_t)i * 40 + c];
#pragma unroll
  for (int off = 1; off < 64; off <<= 1) s += __shfl_xor(s, off);
  __shared__ float red[4];
  if ((threadIdx.x & 63) == 0) red[threadIdx.x >> 6] = s;
  __syncthreads();
  if (threadIdx.x == 0) stats[c] = (red[0] + red[1]) + (red[2] + red[3]);
}

__global__ __launch_bounds__(256) void node_pass2(
    const float* __restrict__ pre, const float* __restrict__ stats,
    const float* __restrict__ bnws, const float* __restrict__ bnbs,
    const float* __restrict__ bnwv, float* __restrict__ out)
{
  int idx = blockIdx.x * blockDim.x + threadIdx.x;
  if (idx >= NN * 40) return;
  int n = idx / 40;
  int c = idx - n * 40;
  float val = pre[idx];
  constexpr float invN = 1.0f / NN;
  if (c < 16) {
    float mu = stats[c] * invN;
    float var = stats[16 + c] * invN - mu * mu;
    out[idx] = (val - mu) * (rsqrtf(var + EPSV) * bnws[c]) + bnbs[c];
  } else {
    int u = (c - 16) / 3;
    float vn = stats[32 + u] * (invN / 3.0f);
    out[idx] = val * (rsqrtf(vn + EPSV) * bnwv[u]);
  }
}

__global__ __launch_bounds__(256) void copy_ef(const f32x4* __restrict__ src,
                                               f32x4* __restrict__ dst) {
  const int n4 = NE * 64 / 4;
  for (int i = blockIdx.x * blockDim.x + threadIdx.x; i < n4;
       i += gridDim.x * blockDim.x)
    dst[i] = src[i];
}

extern "C" void kernel_launch(void* const* d_in, const int* in_sizes, int n_in,
                              void* d_out, int out_size, void* d_ws, size_t ws_size,
                              hipStream_t stream) {
  (void)in_sizes; (void)n_in; (void)out_size;
  const float* nf   = (const float*)d_in[0];
  const float* ef   = (const float*)d_in[1];
  const float* sh   = (const float*)d_in[2];
  const int*   ei   = (const int*)d_in[3];
  const float* w1   = (const float*)d_in[4];
  const float* b1   = (const float*)d_in[5];
  const float* w2   = (const float*)d_in[6];
  const float* b2   = (const float*)d_in[7];
  const float* bnws = (const float*)d_in[8];
  const float* bnbs = (const float*)d_in[9];
  const float* bnwv = (const float*)d_in[10];

  float* out = (float*)d_out;
  float* efout = out + (size_t)NN * 40;

  // ws layout
  char* w = (char*)d_ws;
  int* deg     = (int*)w;                               // NN (zeroed by prep_w2)
  float* stats = (float*)(w + (size_t)NN * 4);          // 40; [44] = b2 flag
  float* flag  = stats + 44;
  int* rowoff  = (int*)(w + (size_t)NN * 4 + 192);      // NN+1
  int* wcur    = rowoff + NN + 1;
  int* perm    = wcur + NN;                             // NE
  float* pre   = (float*)(perm + NE);                   // NN*40
  float* pstats = pre + (size_t)NN * 40;                // GBLK*40
  size_t base  = ((size_t)((char*)(pstats + (size_t)GBLK * 40) - w) + 255) & ~(size_t)255;
  short8* w2bf = (short8*)(w + base);                   // 73728 B
  size_t tpoff = (base + SM_W2 + 255) & ~(size_t)255;

  const size_t TPB = (size_t)NE * TPSTR * 2;            // 20.48 MB (bf16 rows)
  const size_t needA = tpoff + TPB;

  hipFuncSetAttribute((const void*)conv_kernel,
                      hipFuncAttributeMaxDynamicSharedMemorySize, SM_TOTAL);

  prep_w2<<<72 + PREP_DEGB + 1, 64, 0, stream>>>(w2, w2bf, deg, b2, flag);

  const int pblocks = (NN * 40 + 255) / 256;

  hist_kernel<<<625, 256, 0, stream>>>(ei, deg);
  scan_kernel<<<1, 1024, 0, stream>>>(deg, rowoff, wcur);
  fill_kernel<<<625, 256, 0, stream>>>(ei, wcur, perm);

  if (ws_size >= needA) {            // Plan A: tp in ws; ef copy fused in conv
    ushort* tp = (ushort*)(w + tpoff);
    conv_kernel<<<256, 512, SM_TOTAL, stream>>>(
        ef, w1, b1, w2bf, b2, nf, sh, ei, perm, efout, 1, tp, flag);
    gather_kernel<<<GBLK, 256, 0, stream>>>(tp, rowoff, nf, pre, pstats);
    stats_reduce<<<40, 256, 0, stream>>>(pstats, stats);
    node_pass2<<<pblocks, 256, 0, stream>>>(pre, stats, bnws, bnbs, bnwv, out);
  } else {                           // Plan D: tp in efout region; copy ef last
    ushort* tp = (ushort*)efout;                              // 20.48 MB <= 40.9 MB
    conv_kernel<<<256, 512, SM_TOTAL, stream>>>(
        ef, w1, b1, w2bf, b2, nf, sh, ei, perm, efout, 0, tp, flag);
    gather_kernel<<<GBLK, 256, 0, stream>>>(tp, rowoff, nf, pre, pstats);
    stats_reduce<<<40, 256, 0, stream>>>(pstats, stats);
    node_pass2<<<pblocks, 256, 0, stream>>>(pre, stats, bnws, bnbs, bnwv, out);
    copy_ef<<<2048, 256, 0, stream>>>((const f32x4*)ef, (f32x4*)efout);
  }
}

// Round 22
// 86.266 us; speedup vs baseline: 2.1434x; 1.0953x over previous
//
#include <hip/hip_runtime.h>

typedef __attribute__((ext_vector_type(8))) short short8;
typedef __attribute__((ext_vector_type(4))) float f32x4;
typedef __attribute__((ext_vector_type(4))) ushort u16x4;

constexpr int NN = 10000;
constexpr int NE = 160000;
constexpr int NT = NE / 16;                    // 10000 edge-tiles
constexpr int TPSTR = 64;                      // tp row stride in USHORT (128 B = 2 lines)
constexpr int GBLK = 625;                      // gather blocks (625*16 = NN)
constexpr float EPSV = 1e-5f;
constexpr float INV3 = 0.57735026918962576f;   // 1/sqrt(3)
constexpr float ALPHA = 0.20412414523193152f;  // 1/sqrt(16+8)

__device__ __forceinline__ ushort f2bf(float x) {
  unsigned u = __float_as_uint(x);
  u += 0x7fffu + ((u >> 16) & 1u);
  return (ushort)(u >> 16);
}
__device__ __forceinline__ float bf2f(ushort u) {
  return __uint_as_float(((unsigned)u) << 16);
}
__device__ __forceinline__ f32x4 mfma16(short8 a, short8 b, f32x4 c) {
  return __builtin_amdgcn_mfma_f32_16x16x32_bf16(a, b, c, 0, 0, 0);
}
__device__ __forceinline__ void st4u(ushort* p, f32x4 v) {
  u16x4 o;
#pragma unroll
  for (int j = 0; j < 4; ++j) o[j] = f2bf(v[j]);
  *(u16x4*)p = o;
}

// ---------------- K0: W2 -> bf16 A-frags; zero deg; b2 |max| flag ----------------
constexpr int PREP_DEGB = (NN + 63) / 64;      // 157
__global__ __launch_bounds__(64) void prep_w2(const float* __restrict__ w2,
                                              short8* __restrict__ w2bf,
                                              int* __restrict__ deg,
                                              const float* __restrict__ b2,
                                              float* __restrict__ flag) {
  int b = blockIdx.x;
  int lane = threadIdx.x;
  if (b < 72) {                // 72 = 36 jt * 2 kc
    int jt = b >> 1, kc = b & 1;
    int g = lane >> 4, c = lane & 15;
    short8 v;
#pragma unroll
    for (int j = 0; j < 8; ++j)
      v[j] = (short)f2bf(w2[(kc * 32 + 8 * g + j) * 576 + jt * 16 + c]);
    w2bf[(jt * 2 + kc) * 64 + lane] = v;
  } else if (b < 72 + PREP_DEGB) {
    int idx = (b - 72) * 64 + lane;
    if (idx < NN) deg[idx] = 0;
  } else {                     // last block: flag = max|b2|
    float m = 0.f;
    for (int i = lane; i < 576; i += 64) m = fmaxf(m, fabsf(b2[i]));
#pragma unroll
    for (int off = 1; off < 64; off <<= 1) m = fmaxf(m, __shfl_xor(m, off));
    if (lane == 0) *flag = m;
  }
}

// ---------------- K2: FUSED mlp1+conv (r18 proven body; CSR slot via atomic) ----------------
// r22: fill_kernel deleted -- conv assigns its own CSR slot with
// atomicAdd(&wcur[src],1) at store time (same atomic fill did; hides under
// conv's idle pipes). Do NOT add other live state (allocator cap at 96/128).
constexpr int CSTR = 68;
constexpr unsigned SM_W2 = 4608 * 16;                       // 73728 B
constexpr unsigned SM_B2 = 576 * 4;                         // 2304 B
constexpr unsigned SM_W1 = 512 * 16;                        // 8192 B
constexpr unsigned SM_B1 = 64 * 4;                          // 256 B
constexpr unsigned SM_HL = 8 * 16 * 72 * 2;                 // 18432 B (transpose)
constexpr unsigned SM_SCR = 8 * 16 * CSTR * 4;              // 34816 B
constexpr unsigned SM_TOTAL = SM_W2 + SM_B2 + SM_W1 + SM_B1 + SM_HL + SM_SCR; // 137728

__global__ __launch_bounds__(512) void conv_kernel(
    const float* __restrict__ ef, const float* __restrict__ w1,
    const float* __restrict__ b1, const short8* __restrict__ w2bf,
    const float* __restrict__ b2, const float* __restrict__ nf,
    const float* __restrict__ sh, const int* __restrict__ ei,
    int* __restrict__ wcur, float* __restrict__ efout, int do_copy,
    ushort* __restrict__ tp, const float* __restrict__ flagp)
{
  extern __shared__ char smem[];
  short8* w2lds = (short8*)smem;
  float*  b2lds = (float*)(smem + SM_W2);
  short8* w1f   = (short8*)(smem + SM_W2 + SM_B2);
  float*  b1lds = (float*)(smem + SM_W2 + SM_B2 + SM_W1);
  ushort* hlall = (ushort*)(smem + SM_W2 + SM_B2 + SM_W1 + SM_B1);
  float*  scrall = (float*)(smem + SM_W2 + SM_B2 + SM_W1 + SM_B1 + SM_HL);

  const int tid = threadIdx.x;
  for (int i = tid; i < 4608; i += 512) w2lds[i] = w2bf[i];
  for (int i = tid; i < 576; i += 512) b2lds[i] = b2[i];
  {  // W1 -> bf16 B-frags, one per thread (512 frags)
    int tile = tid >> 6, l = tid & 63;
    int nt = tile >> 1, kc = tile & 1;
    int gg = l >> 4, cc = l & 15;
    short8 v;
#pragma unroll
    for (int j = 0; j < 8; ++j)
      v[j] = (short)f2bf(w1[(kc * 32 + 8 * gg + j) * 64 + nt * 16 + cc]);
    w1f[tid] = v;
  }
  if (tid < 64) b1lds[tid] = b1[tid];
  const bool nob2 = (*flagp == 0.f);   // uniform
  __syncthreads();

  const int lane = tid & 63, wid = tid >> 6;
  const int g = lane >> 4, c = lane & 15;
  const int gh = g >> 1;
  const int e = lane >> 2, part = lane & 3;
  float* scr = scrall + wid * (16 * CSTR);
  ushort* hl = hlall + wid * (16 * 72);

  for (int t = blockIdx.x * 8 + wid; t < NT; t += gridDim.x * 8) {
    // ---- phase 0: issue gather loads early (latency hides under MLP1)
    const int ege = t * 16 + e;
    const float* __restrict__ src = nf + (size_t)ei[ege] * 40;
    const f32x4 sv = *(const f32x4*)(sh + (size_t)ege * 4);
    const f32x4 v0 = *(const f32x4*)(src + part * 4);
    const f32x4 v1 = *(const f32x4*)(src + 16 + part * 4);
    f32x4 v2 = {};
    if (part < 2) v2 = *(const f32x4*)(src + 32 + part * 4);

    // ---- phase 1: MLP1 GEMM (lane c = edge of this tile)
    const long ebase = (long)t * 16;
    short8 af[2];
    const float* rowp = ef + (ebase + c) * 64;
#pragma unroll
    for (int kc = 0; kc < 2; ++kc) {
      const f32x4* p = (const f32x4*)(rowp + kc * 32 + 8 * g);
      f32x4 lo = p[0], hi = p[1];
      if (do_copy) {
        f32x4* q = (f32x4*)(efout + (ebase + c) * 64 + kc * 32 + 8 * g);
        q[0] = lo; q[1] = hi;
      }
      short8 v;
#pragma unroll
      for (int j = 0; j < 4; ++j) { v[j] = (short)f2bf(lo[j]); v[4 + j] = (short)f2bf(hi[j]); }
      af[kc] = v;
    }
    f32x4 hacc[4] = {};
#pragma unroll
    for (int nt = 0; nt < 4; ++nt)
#pragma unroll
      for (int kc = 0; kc < 2; ++kc)
        hacc[nt] = mfma16(af[kc], w1f[(nt * 2 + kc) * 64 + lane], hacc[nt]);

    // ---- phase 2: bias+relu, per-wave LDS transpose -> h0/h1 (in-wave ordered)
#pragma unroll
    for (int nt = 0; nt < 4; ++nt) {
      float bv = b1lds[nt * 16 + c];
#pragma unroll
      for (int q = 0; q < 4; ++q) {
        float h = fmaxf(hacc[nt][q] + bv, 0.f);
        hl[(4 * g + q) * 72 + nt * 16 + c] = f2bf(h);
      }
    }
    const short8 h0 = *(const short8*)&hl[c * 72 + 8 * g];
    const short8 h1 = *(const short8*)&hl[c * 72 + 32 + 8 * g];

    // ---- phase 3: coefficient table from phase-0 regs (4 lanes per edge)
    {
      float* ce = scr + e * CSTR;
      f32x4 a0;
#pragma unroll
      for (int q = 0; q < 4; ++q) a0[q] = sv[0] * v0[q];
      *(f32x4*)(ce + 4 * part) = a0;
      *(f32x4*)(ce + 24 + 4 * part) = v0;
      *(f32x4*)(ce + 40 + 4 * part) = v1;
      if (part < 2) *(f32x4*)(ce + 56 + 4 * part) = v2;
#pragma unroll
      for (int uu = 0; uu < 2; ++uu) {
        int u = 2 * part + uu;
        ce[16 + u] = INV3 * (ce[40 + 3 * u] * sv[1] + ce[41 + 3 * u] * sv[2] +
                             ce[42 + 3 * u] * sv[3]);
      }
    }
    const float* __restrict__ cc = scr + c * CSTR;

    // ---- phase 4: j-GEMM + lane-local tensor product
    f32x4 out0acc = {0.f, 0.f, 0.f, 0.f};
    f32x4 c0acc = {0.f, 0.f, 0.f, 0.f};
    f32x4 c1acc[3] = {};

    if (nob2) {  // FAST PATH: zero-init d, independent d0/d1 chains
#pragma unroll
      for (int j4 = 0; j4 < 4; ++j4) {         // w00: u=jt, cc[0..15] vectorized
        const f32x4 a4 = *(const f32x4*)&cc[j4 * 4];
#pragma unroll
        for (int jj = 0; jj < 4; ++jj) {
          const int jt = j4 * 4 + jj;
          f32x4 z = {0.f, 0.f, 0.f, 0.f};
          f32x4 d0 = mfma16(w2lds[(jt * 2 + 0) * 64 + lane], h0, z);
          f32x4 d1 = mfma16(w2lds[(jt * 2 + 1) * 64 + lane], h1, z);
          float a = a4[jj];
#pragma unroll
          for (int q = 0; q < 4; ++q) {
            out0acc[q] = fmaf(a, d0[q], out0acc[q]);
            out0acc[q] = fmaf(a, d1[q], out0acc[q]);
          }
        }
      }
#pragma unroll
      for (int j4 = 0; j4 < 2; ++j4) {         // w11: u=jt-16, cc[16..23] vectorized
        const f32x4 a4 = *(const f32x4*)&cc[16 + j4 * 4];
#pragma unroll
        for (int jj = 0; jj < 4; ++jj) {
          const int jt = 16 + j4 * 4 + jj;
          f32x4 z = {0.f, 0.f, 0.f, 0.f};
          f32x4 d0 = mfma16(w2lds[(jt * 2 + 0) * 64 + lane], h0, z);
          f32x4 d1 = mfma16(w2lds[(jt * 2 + 1) * 64 + lane], h1, z);
          float a = a4[jj];
#pragma unroll
          for (int q = 0; q < 4; ++q) {
            out0acc[q] = fmaf(a, d0[q], out0acc[q]);
            out0acc[q] = fmaf(a, d1[q], out0acc[q]);
          }
        }
      }
#pragma unroll
      for (int jt = 24; jt < 32; ++jt) {       // w01: u=2(jt-24)+gh
        f32x4 z = {0.f, 0.f, 0.f, 0.f};
        f32x4 d0 = mfma16(w2lds[(jt * 2 + 0) * 64 + lane], h0, z);
        f32x4 d1 = mfma16(w2lds[(jt * 2 + 1) * 64 + lane], h1, z);
        float a = cc[24 + 2 * (jt - 24) + gh];
#pragma unroll
        for (int q = 0; q < 4; ++q) {
          c0acc[q] = fmaf(a, d0[q], c0acc[q]);
          c0acc[q] = fmaf(a, d1[q], c0acc[q]);
        }
      }
#pragma unroll
      for (int jt = 32; jt < 36; ++jt) {       // w10: u=2(jt-32)+gh
        f32x4 z = {0.f, 0.f, 0.f, 0.f};
        f32x4 d0 = mfma16(w2lds[(jt * 2 + 0) * 64 + lane], h0, z);
        f32x4 d1 = mfma16(w2lds[(jt * 2 + 1) * 64 + lane], h1, z);
        const int ub = 40 + 3 * (2 * (jt - 32) + gh);
#pragma unroll
        for (int i = 0; i < 3; ++i) {
          float a = cc[ub + i];
#pragma unroll
          for (int q = 0; q < 4; ++q) {
            c1acc[i][q] = fmaf(a, d0[q], c1acc[i][q]);
            c1acc[i][q] = fmaf(a, d1[q], c1acc[i][q]);
          }
        }
      }
    } else {     // GENERAL PATH (b2 != 0): bias in C operand
#pragma unroll
      for (int jt = 0; jt < 16; ++jt) {
        f32x4 d = *(const f32x4*)&b2lds[jt * 16 + 4 * g];
        d = mfma16(w2lds[(jt * 2 + 0) * 64 + lane], h0, d);
        d = mfma16(w2lds[(jt * 2 + 1) * 64 + lane], h1, d);
        float a = cc[jt];
#pragma unroll
        for (int q = 0; q < 4; ++q) out0acc[q] = fmaf(a, d[q], out0acc[q]);
      }
#pragma unroll
      for (int jt = 16; jt < 24; ++jt) {
        f32x4 d = *(const f32x4*)&b2lds[jt * 16 + 4 * g];
        d = mfma16(w2lds[(jt * 2 + 0) * 64 + lane], h0, d);
        d = mfma16(w2lds[(jt * 2 + 1) * 64 + lane], h1, d);
        float a = cc[16 + (jt - 16)];
#pragma unroll
        for (int q = 0; q < 4; ++q) out0acc[q] = fmaf(a, d[q], out0acc[q]);
      }
#pragma unroll
      for (int jt = 24; jt < 32; ++jt) {
        f32x4 d = *(const f32x4*)&b2lds[jt * 16 + 4 * g];
        d = mfma16(w2lds[(jt * 2 + 0) * 64 + lane], h0, d);
        d = mfma16(w2lds[(jt * 2 + 1) * 64 + lane], h1, d);
        float a = cc[24 + 2 * (jt - 24) + gh];
#pragma unroll
        for (int q = 0; q < 4; ++q) c0acc[q] = fmaf(a, d[q], c0acc[q]);
      }
#pragma unroll
      for (int jt = 32; jt < 36; ++jt) {
        f32x4 d = *(const f32x4*)&b2lds[jt * 16 + 4 * g];
        d = mfma16(w2lds[(jt * 2 + 0) * 64 + lane], h0, d);
        d = mfma16(w2lds[(jt * 2 + 1) * 64 + lane], h1, d);
        const int ub = 40 + 3 * (2 * (jt - 32) + gh);
#pragma unroll
        for (int i = 0; i < 3; ++i) {
          float a = cc[ub + i];
#pragma unroll
          for (int q = 0; q < 4; ++q) c1acc[i][q] = fmaf(a, d[q], c1acc[i][q]);
        }
      }
    }

    // fold gh halves (lane ^ 32)
#pragma unroll
    for (int q = 0; q < 4; ++q) c0acc[q] += __shfl_xor(c0acc[q], 32);
#pragma unroll
    for (int i = 0; i < 3; ++i)
#pragma unroll
      for (int q = 0; q < 4; ++q) c1acc[i][q] += __shfl_xor(c1acc[i][q], 32);

    // ---- store: claim this edge's CSR slot (atomic; replaces fill_kernel)
    const int eg = t * 16 + c;
    const f32x4 shv = *(const f32x4*)(sh + (size_t)eg * 4);
    int pos = 0;
    if (g == 0) pos = atomicAdd(&wcur[ei[NE + eg]], 1);   // one lane per edge
    pos = __shfl(pos, c);                                  // broadcast to all g
    ushort* tpr = tp + (size_t)pos * TPSTR;
    f32x4 o0;
#pragma unroll
    for (int q = 0; q < 4; ++q) o0[q] = ALPHA * out0acc[q];
    st4u(tpr + 4 * g, o0);
    if (g < 2) {
      float wv[12];
#pragma unroll
      for (int q = 0; q < 4; ++q)
#pragma unroll
        for (int i = 0; i < 3; ++i)
          wv[q * 3 + i] = ALPHA * (shv[1 + i] * c0acc[q] + shv[0] * c1acc[i][q]);
#pragma unroll
      for (int p = 0; p < 3; ++p) {
        f32x4 v = {wv[4 * p], wv[4 * p + 1], wv[4 * p + 2], wv[4 * p + 3]};
        st4u(tpr + 16 + 12 * g + 4 * p, v);
      }
    }
  }
}

// ---------------- CSR build ----------------
__global__ __launch_bounds__(256) void hist_kernel(const int* __restrict__ ei,
                                                   int* __restrict__ deg) {
  for (int e = blockIdx.x * 256 + threadIdx.x; e < NE; e += gridDim.x * 256)
    atomicAdd(&deg[ei[NE + e]], 1);
}

// wave-level shfl_up scan, 2 barriers total
__global__ __launch_bounds__(1024) void scan_kernel(const int* __restrict__ deg,
                                                    int* __restrict__ rowoff,
                                                    int* __restrict__ wcur) {
  __shared__ int wsum[16];
  const int t = threadIdx.x;
  const int lane = t & 63, wid = t >> 6;
  const int base = t * 10;
  int d[10];
  int sum = 0;
#pragma unroll
  for (int j = 0; j < 10; ++j) {
    int n = base + j;
    d[j] = (n < NN) ? deg[n] : 0;
    sum += d[j];
  }
  int val = sum;                       // inclusive scan within wave
#pragma unroll
  for (int off = 1; off < 64; off <<= 1) {
    int v = __shfl_up(val, off);
    if (lane >= off) val += v;
  }
  if (lane == 63) wsum[wid] = val;
  __syncthreads();
  if (t < 16) {
    int v = wsum[t];
#pragma unroll
    for (int off = 1; off < 16; off <<= 1) {
      int u = __shfl_up(v, off);
      if (t >= off) v += u;
    }
    wsum[t] = v;                       // inclusive over waves
  }
  __syncthreads();
  const int waveoff = (wid > 0) ? wsum[wid - 1] : 0;
  int run = waveoff + (val - sum);     // exclusive prefix for this thread
#pragma unroll
  for (int j = 0; j < 10; ++j) {
    int n = base + j;
    if (n < NN) { rowoff[n] = run; wcur[n] = run; }
    run += d[j];
  }
  if (t == 1023) rowoff[NN] = run;
}

// ---------------- gather: linear CSR bf16 rows; per-block pstats (non-atomic) ----------------
__global__ __launch_bounds__(256) void gather_kernel(
    const ushort* __restrict__ tp, const int* __restrict__ rowoff,
    const float* __restrict__ nf, float* __restrict__ pre,
    float* __restrict__ pstats)
{
  __shared__ float ls[40];
  const int tid = threadIdx.x;
  if (tid < 40) ls[tid] = 0.f;
  __syncthreads();
  const int wid = tid >> 6, lane = tid & 63;
  float sacc = 0.f, qacc = 0.f;
  if (lane < 40) {
#pragma unroll 1
    for (int i = 0; i < 4; ++i) {
      const int n = blockIdx.x * 16 + wid * 4 + i;   // GBLK*16 == NN exactly
      const int r0 = rowoff[n], r1 = rowoff[n + 1];
      float s0 = 0.f, s1 = 0.f, s2 = 0.f, s3 = 0.f,
            s4 = 0.f, s5 = 0.f, s6 = 0.f, s7 = 0.f;
      int k = r0;
      for (; k + 8 <= r1; k += 8) {
        s0 += bf2f(tp[(size_t)(k + 0) * TPSTR + lane]);
        s1 += bf2f(tp[(size_t)(k + 1) * TPSTR + lane]);
        s2 += bf2f(tp[(size_t)(k + 2) * TPSTR + lane]);
        s3 += bf2f(tp[(size_t)(k + 3) * TPSTR + lane]);
        s4 += bf2f(tp[(size_t)(k + 4) * TPSTR + lane]);
        s5 += bf2f(tp[(size_t)(k + 5) * TPSTR + lane]);
        s6 += bf2f(tp[(size_t)(k + 6) * TPSTR + lane]);
        s7 += bf2f(tp[(size_t)(k + 7) * TPSTR + lane]);
      }
      for (; k < r1; ++k) s0 += bf2f(tp[(size_t)k * TPSTR + lane]);
      float s = ((s0 + s1) + (s2 + s3)) + ((s4 + s5) + (s6 + s7));
      float val = s / fmaxf((float)(r1 - r0), 1.f) + nf[(size_t)n * 40 + lane];
      pre[(size_t)n * 40 + lane] = val;
      if (lane < 16) { sacc += val; qacc += val * val; }
      else qacc += val * val;
    }
    if (lane < 16) {
      atomicAdd(&ls[lane], sacc);
      atomicAdd(&ls[16 + lane], qacc);
    } else {
      atomicAdd(&ls[32 + (lane - 16) / 3], qacc);
    }
  }
  __syncthreads();
  if (tid < 40) pstats[(size_t)blockIdx.x * 40 + tid] = ls[tid];
}

// 40 blocks: channel c = blockIdx; sum 625 block-partials
__global__ __launch_bounds__(256) void stats_reduce(
    const float* __restrict__ pstats, float* __restrict__ stats)
{
  const int c = blockIdx.x;
  float s = 0.f;
  for (int i = threadIdx.x; i < GBLK; i += 256) s += pstats[(size_t)i * 40 + c];
#pragma unroll
  for (int off = 1; off < 64; off <<= 1) s += __shfl_xor(s, off);
  __shared__ float red[4];
  if ((threadIdx.x & 63) == 0) red[threadIdx.x >> 6] = s;
  __syncthreads();
  if (threadIdx.x == 0) stats[c] = (red[0] + red[1]) + (red[2] + red[3]);
}

__global__ __launch_bounds__(256) void node_pass2(
    const float* __restrict__ pre, const float* __restrict__ stats,
    const float* __restrict__ bnws, const float* __restrict__ bnbs,
    const float* __restrict__ bnwv, float* __restrict__ out)
{
  int idx = blockIdx.x * blockDim.x + threadIdx.x;
  if (idx >= NN * 40) return;
  int n = idx / 40;
  int c = idx - n * 40;
  float val = pre[idx];
  constexpr float invN = 1.0f / NN;
  if (c < 16) {
    float mu = stats[c] * invN;
    float var = stats[16 + c] * invN - mu * mu;
    out[idx] = (val - mu) * (rsqrtf(var + EPSV) * bnws[c]) + bnbs[c];
  } else {
    int u = (c - 16) / 3;
    float vn = stats[32 + u] * (invN / 3.0f);
    out[idx] = val * (rsqrtf(vn + EPSV) * bnwv[u]);
  }
}

__global__ __launch_bounds__(256) void copy_ef(const f32x4* __restrict__ src,
                                               f32x4* __restrict__ dst) {
  const int n4 = NE * 64 / 4;
  for (int i = blockIdx.x * blockDim.x + threadIdx.x; i < n4;
       i += gridDim.x * blockDim.x)
    dst[i] = src[i];
}

extern "C" void kernel_launch(void* const* d_in, const int* in_sizes, int n_in,
                              void* d_out, int out_size, void* d_ws, size_t ws_size,
                              hipStream_t stream) {
  (void)in_sizes; (void)n_in; (void)out_size;
  const float* nf   = (const float*)d_in[0];
  const float* ef   = (const float*)d_in[1];
  const float* sh   = (const float*)d_in[2];
  const int*   ei   = (const int*)d_in[3];
  const float* w1   = (const float*)d_in[4];
  const float* b1   = (const float*)d_in[5];
  const float* w2   = (const float*)d_in[6];
  const float* b2   = (const float*)d_in[7];
  const float* bnws = (const float*)d_in[8];
  const float* bnbs = (const float*)d_in[9];
  const float* bnwv = (const float*)d_in[10];

  float* out = (float*)d_out;
  float* efout = out + (size_t)NN * 40;

  // ws layout
  char* w = (char*)d_ws;
  int* deg     = (int*)w;                               // NN (zeroed by prep_w2)
  float* stats = (float*)(w + (size_t)NN * 4);          // 40; [44] = b2 flag
  float* flag  = stats + 44;
  int* rowoff  = (int*)(w + (size_t)NN * 4 + 192);      // NN+1
  int* wcur    = rowoff + NN + 1;
  float* pre   = (float*)(wcur + NN);                   // NN*40
  float* pstats = pre + (size_t)NN * 40;                // GBLK*40
  size_t base  = ((size_t)((char*)(pstats + (size_t)GBLK * 40) - w) + 255) & ~(size_t)255;
  short8* w2bf = (short8*)(w + base);                   // 73728 B
  size_t tpoff = (base + SM_W2 + 255) & ~(size_t)255;

  const size_t TPB = (size_t)NE * TPSTR * 2;            // 20.48 MB (bf16 rows)
  const size_t needA = tpoff + TPB;

  hipFuncSetAttribute((const void*)conv_kernel,
                      hipFuncAttributeMaxDynamicSharedMemorySize, SM_TOTAL);

  prep_w2<<<72 + PREP_DEGB + 1, 64, 0, stream>>>(w2, w2bf, deg, b2, flag);

  const int pblocks = (NN * 40 + 255) / 256;

  hist_kernel<<<625, 256, 0, stream>>>(ei, deg);
  scan_kernel<<<1, 1024, 0, stream>>>(deg, rowoff, wcur);

  if (ws_size >= needA) {            // Plan A: tp in ws; ef copy fused in conv
    ushort* tp = (ushort*)(w + tpoff);
    conv_kernel<<<256, 512, SM_TOTAL, stream>>>(
        ef, w1, b1, w2bf, b2, nf, sh, ei, wcur, efout, 1, tp, flag);
    gather_kernel<<<GBLK, 256, 0, stream>>>(tp, rowoff, nf, pre, pstats);
    stats_reduce<<<40, 256, 0, stream>>>(pstats, stats);
    node_pass2<<<pblocks, 256, 0, stream>>>(pre, stats, bnws, bnbs, bnwv, out);
  } else {                           // Plan D: tp in efout region; copy ef last
    ushort* tp = (ushort*)efout;                              // 20.48 MB <= 40.9 MB
    conv_kernel<<<256, 512, SM_TOTAL, stream>>>(
        ef, w1, b1, w2bf, b2, nf, sh, ei, wcur, efout, 0, tp, flag);
    gather_kernel<<<GBLK, 256, 0, stream>>>(tp, rowoff, nf, pre, pstats);
    stats_reduce<<<40, 256, 0, stream>>>(pstats, stats);
    node_pass2<<<pblocks, 256, 0, stream>>>(pre, stats, bnws, bnbs, bnwv, out);
    copy_ef<<<2048, 256, 0, stream>>>((const f32x4*)ef, (f32x4*)efout);
  }
}